// Round 1
// baseline (708.745 us; speedup 1.0000x reference)
//
#include <hip/hip_runtime.h>
#include <math.h>

// Problem constants (fixed by reference file)
#define NB   2
#define LQ   16384
#define CDIM 256
#define MH   8          // heads
#define DH   32         // head dim
#define LIN  21760      // 128^2+64^2+32^2+16^2

// ---------------- f32 tiled GEMM: C = A(MxK) @ B(KxN) + bias ----------------
// Row-major everywhere. M%64==0, N%64==0, K%16==0 guaranteed by problem sizes.
#define BM 64
#define BN 64
#define BK 16

__global__ __launch_bounds__(256) void gemm_f32(
    const float* __restrict__ A, const float* __restrict__ B,
    const float* __restrict__ bias, float* __restrict__ C,
    int M, int N, int K)
{
    __shared__ float As[BK][BM];   // [k][m]
    __shared__ float Bs[BK][BN];   // [k][n]

    const int bn = blockIdx.x * BN;
    const int bm = blockIdx.y * BM;
    const int tid = threadIdx.x;
    const int tx = tid & 15;       // 0..15 -> 4 cols each
    const int ty = tid >> 4;       // 0..15 -> 4 rows each

    float acc[4][4] = {};

    for (int k0 = 0; k0 < K; k0 += BK) {
        // Stage A tile (64 rows x 16 k): each thread one float4 along k
        {
            const int r  = tid >> 2;            // 0..63
            const int kk = (tid & 3) << 2;      // 0,4,8,12
            float4 v = *(const float4*)&A[(size_t)(bm + r) * K + k0 + kk];
            As[kk + 0][r] = v.x;
            As[kk + 1][r] = v.y;
            As[kk + 2][r] = v.z;
            As[kk + 3][r] = v.w;
        }
        // Stage B tile (16 k x 64 n): each thread one float4 along n
        {
            const int kk = tid >> 4;            // 0..15
            const int c  = (tid & 15) << 2;     // 0..60
            float4 v = *(const float4*)&B[(size_t)(k0 + kk) * N + bn + c];
            *(float4*)&Bs[kk][c] = v;
        }
        __syncthreads();

        #pragma unroll
        for (int kk = 0; kk < BK; ++kk) {
            const float4 a4 = *(const float4*)&As[kk][ty << 2];
            const float4 b4 = *(const float4*)&Bs[kk][tx << 2];
            const float a[4] = {a4.x, a4.y, a4.z, a4.w};
            const float b[4] = {b4.x, b4.y, b4.z, b4.w};
            #pragma unroll
            for (int i = 0; i < 4; ++i)
                #pragma unroll
                for (int j = 0; j < 4; ++j)
                    acc[i][j] += a[i] * b[j];
        }
        __syncthreads();
    }

    // Epilogue: += bias, vectorized store
    const float4 bia = *(const float4*)&bias[bn + (tx << 2)];
    #pragma unroll
    for (int i = 0; i < 4; ++i) {
        const int r = bm + (ty << 2) + i;
        float4 o;
        o.x = acc[i][0] + bia.x;
        o.y = acc[i][1] + bia.y;
        o.z = acc[i][2] + bia.z;
        o.w = acc[i][3] + bia.w;
        *(float4*)&C[(size_t)r * N + bn + (tx << 2)] = o;
    }
}

// ---------------- softmax over last-16, in place ----------------
__global__ __launch_bounds__(256) void softmax16_kernel(float* __restrict__ a, int rows)
{
    const int r = blockIdx.x * 256 + threadIdx.x;
    if (r >= rows) return;
    float* row = a + (size_t)r * 16;
    float v[16];
    float4* rv = (float4*)row;
    #pragma unroll
    for (int i = 0; i < 4; ++i) *(float4*)&v[i * 4] = rv[i];
    float mx = v[0];
    #pragma unroll
    for (int i = 1; i < 16; ++i) mx = fmaxf(mx, v[i]);
    float s = 0.f;
    #pragma unroll
    for (int i = 0; i < 16; ++i) { v[i] = __expf(v[i] - mx); s += v[i]; }
    const float inv = 1.f / s;
    #pragma unroll
    for (int i = 0; i < 16; ++i) v[i] *= inv;
    #pragma unroll
    for (int i = 0; i < 4; ++i) rv[i] = *(float4*)&v[i * 4];
}

// ---------------- deformable sampling + weighted aggregation ----------------
// One block per (n, lq); thread = (m = tid/32, d = tid%32).
// value  : (N, LIN, 256)  [channel = m*32+d]
// off    : (N, LQ, 256)   [((m*4+l)*4+p)*2 + {x,y}]
// attn   : (N, LQ, 128)   softmaxed, [m*16 + j] where j indexes (L,P) as l*4+p
// NOTE (reference quirk): sample (l,p) is weighted by attn[..., p, l]
//      because vals flattens (P,L) while w flattens (L,P).
__global__ __launch_bounds__(256) void sample_kernel(
    const float* __restrict__ value,
    const float* __restrict__ off,
    const float* __restrict__ attn,
    float* __restrict__ out)
{
    const int blk = blockIdx.x;        // 0 .. N*LQ-1
    const int lq  = blk & (LQ - 1);
    const int n   = blk >> 14;
    const int tid = threadIdx.x;
    const int d   = tid & 31;
    const int m   = tid >> 5;

    const float* off_row  = off  + (size_t)blk * 256 + m * 32;
    const float* attn_row = attn + (size_t)blk * 128 + m * 16;

    const float refx = ((lq & 127) + 0.5f) * (1.0f / 128.0f);
    const float refy = ((lq >> 7)  + 0.5f) * (1.0f / 128.0f);

    const int HS[4]     = {128, 64, 32, 16};
    const int STARTS[4] = {0, 16384, 20480, 21504};

    float acc = 0.f;
    #pragma unroll
    for (int l = 0; l < 4; ++l) {
        const int Hl = HS[l];                 // square levels: W == H
        const float* vbase = value + ((size_t)(n * LIN + STARTS[l]) * 256) + m * 32 + d;
        #pragma unroll
        for (int p = 0; p < 4; ++p) {
            const float ox = off_row[(l * 4 + p) * 2 + 0];
            const float oy = off_row[(l * 4 + p) * 2 + 1];
            const float w  = attn_row[p * 4 + l];   // transposed pairing (see note)

            const float x = refx * (float)Hl + ox - 0.5f;
            const float y = refy * (float)Hl + oy - 0.5f;
            const float x0f = floorf(x), y0f = floorf(y);
            const int x0 = (int)x0f, y0 = (int)y0f;
            const int x1 = x0 + 1,  y1 = y0 + 1;
            const float fx = x - x0f, fy = y - y0f;
            const float gx = 1.f - fx, gy = 1.f - fy;

            const bool vx0 = (x0 >= 0) & (x0 < Hl);
            const bool vx1 = (x1 >= 0) & (x1 < Hl);
            const bool vy0 = (y0 >= 0) & (y0 < Hl);
            const bool vy1 = (y1 >= 0) & (y1 < Hl);

            float v00 = 0.f, v01 = 0.f, v10 = 0.f, v11 = 0.f;
            if (vy0) {
                const float* r0 = vbase + (size_t)y0 * Hl * 256;
                if (vx0) v00 = r0[(size_t)x0 * 256];
                if (vx1) v01 = r0[(size_t)x1 * 256];
            }
            if (vy1) {
                const float* r1 = vbase + (size_t)y1 * Hl * 256;
                if (vx0) v10 = r1[(size_t)x0 * 256];
                if (vx1) v11 = r1[(size_t)x1 * 256];
            }
            acc += w * (gy * (gx * v00 + fx * v01) + fy * (gx * v10 + fx * v11));
        }
    }
    out[(size_t)blk * 256 + m * 32 + d] = acc;
}

// ---------------- launch ----------------
extern "C" void kernel_launch(void* const* d_in, const int* in_sizes, int n_in,
                              void* d_out, int out_size, void* d_ws, size_t ws_size,
                              hipStream_t stream)
{
    const float* query         = (const float*)d_in[0];
    // d_in[1] reference_points: unused by reference._forward
    const float* input_flatten = (const float*)d_in[2];
    // d_in[3] spatial_shapes, d_in[4] level_start_index: compile-time constants
    const float* W_off  = (const float*)d_in[5];
    const float* b_off  = (const float*)d_in[6];
    const float* W_attn = (const float*)d_in[7];
    const float* b_attn = (const float*)d_in[8];
    const float* W_val  = (const float*)d_in[9];
    const float* b_val  = (const float*)d_in[10];
    const float* W_out  = (const float*)d_in[11];
    const float* b_out  = (const float*)d_in[12];
    float* out = (float*)d_out;

    // Workspace layout (floats):
    //   value   : 43520*256 = 11,141,120
    //   attn    : 32768*128 =  4,194,304
    //   sampled : 32768*256 =  8,388,608
    // off (32768*256) is staged in d_out (same size), consumed before the
    // final GEMM overwrites d_out.
    float* ws      = (float*)d_ws;
    float* value   = ws;
    float* attnbuf = value + (size_t)43520 * 256;
    float* sampled = attnbuf + (size_t)32768 * 128;
    float* offbuf  = out;   // staged in d_out

    const int rowsA = NB * LQ;          // 32768
    const int rowsV = NB * LIN;         // 43520

    dim3 blk(256);

    // 1) value = input_flatten @ W_val + b_val
    gemm_f32<<<dim3(CDIM / BN, rowsV / BM), blk, 0, stream>>>(
        input_flatten, W_val, b_val, value, rowsV, CDIM, CDIM);

    // 2) off = query @ W_off + b_off   (into d_out scratch)
    gemm_f32<<<dim3(CDIM / BN, rowsA / BM), blk, 0, stream>>>(
        query, W_off, b_off, offbuf, rowsA, CDIM, CDIM);

    // 3) attn logits = query @ W_attn + b_attn
    gemm_f32<<<dim3(128 / BN, rowsA / BM), blk, 0, stream>>>(
        query, W_attn, b_attn, attnbuf, rowsA, 128, CDIM);

    // 4) softmax over 16 per (n,lq,m)
    softmax16_kernel<<<(rowsA * MH + 255) / 256, blk, 0, stream>>>(
        attnbuf, rowsA * MH);

    // 5) deformable sampling + aggregation
    sample_kernel<<<rowsA, blk, 0, stream>>>(value, offbuf, attnbuf, sampled);

    // 6) out = sampled @ W_out + b_out
    gemm_f32<<<dim3(CDIM / BN, rowsA / BM), blk, 0, stream>>>(
        sampled, W_out, b_out, out, rowsA, CDIM, CDIM);
}

// Round 2
// 650.312 us; speedup vs baseline: 1.0899x; 1.0899x over previous
//
#include <hip/hip_runtime.h>
#include <math.h>

// Problem constants (fixed by reference file)
#define NB   2
#define LQ   16384
#define CDIM 256
#define MH   8          // heads
#define DH   32         // head dim
#define LIN  21760      // 128^2+64^2+32^2+16^2

// ---------------- f32 tiled GEMM: C = A(MxK) @ B(KxN) + bias ----------------
#define BM 64
#define BN 64
#define BK 16

__global__ __launch_bounds__(256) void gemm_f32(
    const float* __restrict__ A, const float* __restrict__ B,
    const float* __restrict__ bias, float* __restrict__ C,
    int M, int N, int K)
{
    __shared__ float As[BK][BM];   // [k][m]
    __shared__ float Bs[BK][BN];   // [k][n]

    const int bn = blockIdx.x * BN;
    const int bm = blockIdx.y * BM;
    const int tid = threadIdx.x;
    const int tx = tid & 15;       // 0..15 -> 4 cols each
    const int ty = tid >> 4;       // 0..15 -> 4 rows each

    float acc[4][4] = {};

    for (int k0 = 0; k0 < K; k0 += BK) {
        {
            const int r  = tid >> 2;            // 0..63
            const int kk = (tid & 3) << 2;      // 0,4,8,12
            float4 v = *(const float4*)&A[(size_t)(bm + r) * K + k0 + kk];
            As[kk + 0][r] = v.x;
            As[kk + 1][r] = v.y;
            As[kk + 2][r] = v.z;
            As[kk + 3][r] = v.w;
        }
        {
            const int kk = tid >> 4;            // 0..15
            const int c  = (tid & 15) << 2;     // 0..60
            float4 v = *(const float4*)&B[(size_t)(k0 + kk) * N + bn + c];
            *(float4*)&Bs[kk][c] = v;
        }
        __syncthreads();

        #pragma unroll
        for (int kk = 0; kk < BK; ++kk) {
            const float4 a4 = *(const float4*)&As[kk][ty << 2];
            const float4 b4 = *(const float4*)&Bs[kk][tx << 2];
            const float a[4] = {a4.x, a4.y, a4.z, a4.w};
            const float b[4] = {b4.x, b4.y, b4.z, b4.w};
            #pragma unroll
            for (int i = 0; i < 4; ++i)
                #pragma unroll
                for (int j = 0; j < 4; ++j)
                    acc[i][j] += a[i] * b[j];
        }
        __syncthreads();
    }

    const float4 bia = *(const float4*)&bias[bn + (tx << 2)];
    #pragma unroll
    for (int i = 0; i < 4; ++i) {
        const int r = bm + (ty << 2) + i;
        float4 o;
        o.x = acc[i][0] + bia.x;
        o.y = acc[i][1] + bia.y;
        o.z = acc[i][2] + bia.z;
        o.w = acc[i][3] + bia.w;
        *(float4*)&C[(size_t)r * N + bn + (tx << 2)] = o;
    }
}

// ---------------- softmax over last-16, in place ----------------
__global__ __launch_bounds__(256) void softmax16_kernel(float* __restrict__ a, int rows)
{
    const int r = blockIdx.x * 256 + threadIdx.x;
    if (r >= rows) return;
    float* row = a + (size_t)r * 16;
    float v[16];
    float4* rv = (float4*)row;
    #pragma unroll
    for (int i = 0; i < 4; ++i) *(float4*)&v[i * 4] = rv[i];
    float mx = v[0];
    #pragma unroll
    for (int i = 1; i < 16; ++i) mx = fmaxf(mx, v[i]);
    float s = 0.f;
    #pragma unroll
    for (int i = 0; i < 16; ++i) { v[i] = __expf(v[i] - mx); s += v[i]; }
    const float inv = 1.f / s;
    #pragma unroll
    for (int i = 0; i < 16; ++i) v[i] *= inv;
    #pragma unroll
    for (int i = 0; i < 4; ++i) rv[i] = *(float4*)&v[i * 4];
}

// ---------------- deformable sampling + weighted aggregation (v2) ----------------
// 4 queries per 256-thread block. Thread = (q_local = tid/64, m = (tid>>3)&7,
// d4 = tid&7). Each thread owns 4 channels (float4) of one head.
// value  : (N, LIN, 256)  [channel = m*32 + d4*4 .. +3]
// off    : (N, LQ, 256)   [((m*4+l)*4+p)*2 + {x,y}]
// attn   : (N, LQ, 128)   softmaxed, [m*16 + j], j = l*4+p
// Reference quirk: sample (l,p) is weighted by attn[..., p, l] (vals flattens
// (P,L) while w flattens (L,P)).
__global__ __launch_bounds__(256) void sample_kernel_v2(
    const float* __restrict__ value,
    const float* __restrict__ off,
    const float* __restrict__ attn,
    float* __restrict__ out)
{
    const int tid = threadIdx.x;
    const int qi  = blockIdx.x * 4 + (tid >> 6);   // 0 .. N*LQ-1
    const int lq  = qi & (LQ - 1);
    const int n   = qi >> 14;
    const int m   = (tid >> 3) & 7;
    const int d4  = tid & 7;

    const float* off_row  = off  + (size_t)qi * 256 + m * 32;
    const float* attn_row = attn + (size_t)qi * 128 + m * 16;

    const float refx = ((lq & 127) + 0.5f) * (1.0f / 128.0f);
    const float refy = ((lq >> 7)  + 0.5f) * (1.0f / 128.0f);

    const int STARTS[4] = {0, 16384, 20480, 21504};

    float4 acc = {0.f, 0.f, 0.f, 0.f};
    #pragma unroll
    for (int l = 0; l < 4; ++l) {
        const int Hl = 128 >> l;                  // square levels: W == H
        const float* vbase = value + ((size_t)(n * LIN + STARTS[l]) * 256)
                                   + m * 32 + d4 * 4;
        #pragma unroll
        for (int p = 0; p < 4; ++p) {
            const float2 oxy = *(const float2*)&off_row[(l * 4 + p) * 2];
            const float w    = attn_row[p * 4 + l];   // transposed pairing

            const float x = refx * (float)Hl + oxy.x - 0.5f;
            const float y = refy * (float)Hl + oxy.y - 0.5f;
            const float x0f = floorf(x), y0f = floorf(y);
            const int x0 = (int)x0f, y0 = (int)y0f;
            const int x1 = x0 + 1,  y1 = y0 + 1;
            const float fx = x - x0f, fy = y - y0f;
            const float gx = 1.f - fx, gy = 1.f - fy;

            // combined corner weights (include attn weight once)
            const float w00 = w * gy * gx;
            const float w01 = w * gy * fx;
            const float w10 = w * fy * gx;
            const float w11 = w * fy * fx;

            const bool vx0 = (x0 >= 0) & (x0 < Hl);
            const bool vx1 = (x1 >= 0) & (x1 < Hl);
            const bool vy0 = (y0 >= 0) & (y0 < Hl);
            const bool vy1 = (y1 >= 0) & (y1 < Hl);

            float4 z = {0.f, 0.f, 0.f, 0.f};
            float4 v00 = z, v01 = z, v10 = z, v11 = z;
            if (vy0) {
                const float* r0 = vbase + (size_t)y0 * Hl * 256;
                if (vx0) v00 = *(const float4*)&r0[(size_t)x0 * 256];
                if (vx1) v01 = *(const float4*)&r0[(size_t)x1 * 256];
            }
            if (vy1) {
                const float* r1 = vbase + (size_t)y1 * Hl * 256;
                if (vx0) v10 = *(const float4*)&r1[(size_t)x0 * 256];
                if (vx1) v11 = *(const float4*)&r1[(size_t)x1 * 256];
            }
            acc.x += w00 * v00.x + w01 * v01.x + w10 * v10.x + w11 * v11.x;
            acc.y += w00 * v00.y + w01 * v01.y + w10 * v10.y + w11 * v11.y;
            acc.z += w00 * v00.z + w01 * v01.z + w10 * v10.z + w11 * v11.z;
            acc.w += w00 * v00.w + w01 * v01.w + w10 * v10.w + w11 * v11.w;
        }
    }
    *(float4*)&out[(size_t)qi * 256 + m * 32 + d4 * 4] = acc;
}

// ---------------- launch ----------------
extern "C" void kernel_launch(void* const* d_in, const int* in_sizes, int n_in,
                              void* d_out, int out_size, void* d_ws, size_t ws_size,
                              hipStream_t stream)
{
    const float* query         = (const float*)d_in[0];
    const float* input_flatten = (const float*)d_in[2];
    const float* W_off  = (const float*)d_in[5];
    const float* b_off  = (const float*)d_in[6];
    const float* W_attn = (const float*)d_in[7];
    const float* b_attn = (const float*)d_in[8];
    const float* W_val  = (const float*)d_in[9];
    const float* b_val  = (const float*)d_in[10];
    const float* W_out  = (const float*)d_in[11];
    const float* b_out  = (const float*)d_in[12];
    float* out = (float*)d_out;

    // Workspace layout (floats): value | attn | sampled. off staged in d_out.
    float* ws      = (float*)d_ws;
    float* value   = ws;
    float* attnbuf = value + (size_t)43520 * 256;
    float* sampled = attnbuf + (size_t)32768 * 128;
    float* offbuf  = out;   // consumed before final GEMM overwrites d_out

    const int rowsA = NB * LQ;          // 32768
    const int rowsV = NB * LIN;         // 43520

    dim3 blk(256);

    // 1) value = input_flatten @ W_val + b_val
    gemm_f32<<<dim3(CDIM / BN, rowsV / BM), blk, 0, stream>>>(
        input_flatten, W_val, b_val, value, rowsV, CDIM, CDIM);

    // 2) off = query @ W_off + b_off   (into d_out scratch)
    gemm_f32<<<dim3(CDIM / BN, rowsA / BM), blk, 0, stream>>>(
        query, W_off, b_off, offbuf, rowsA, CDIM, CDIM);

    // 3) attn logits = query @ W_attn + b_attn
    gemm_f32<<<dim3(128 / BN, rowsA / BM), blk, 0, stream>>>(
        query, W_attn, b_attn, attnbuf, rowsA, 128, CDIM);

    // 4) softmax over 16 per (n,lq,m)
    softmax16_kernel<<<(rowsA * MH + 255) / 256, blk, 0, stream>>>(
        attnbuf, rowsA * MH);

    // 5) deformable sampling + aggregation (v2: float4 channels)
    sample_kernel_v2<<<rowsA / 4, blk, 0, stream>>>(value, offbuf, attnbuf, sampled);

    // 6) out = sampled @ W_out + b_out
    gemm_f32<<<dim3(CDIM / BN, rowsA / BM), blk, 0, stream>>>(
        sampled, W_out, b_out, out, rowsA, CDIM, CDIM);
}

// Round 3
// 450.231 us; speedup vs baseline: 1.5742x; 1.4444x over previous
//
#include <hip/hip_runtime.h>
#include <math.h>

// Problem constants (fixed by reference file)
#define NB   2
#define LQ   16384
#define CDIM 256
#define MH   8          // heads
#define DH   32         // head dim
#define LIN  21760      // 128^2+64^2+32^2+16^2

// ---------------- f32 tiled GEMM: C = A(MxK) @ B(KxN) + bias ----------------
// BM=128, BN=64, BK=16; 256 threads; 8x4 accumulator per thread.
#define BM 128
#define BN 64
#define BK 16

__global__ __launch_bounds__(256) void gemm_f32(
    const float* __restrict__ A, const float* __restrict__ B,
    const float* __restrict__ bias, float* __restrict__ C,
    int M, int N, int K)
{
    __shared__ float As[BK][BM];   // [k][m]
    __shared__ float Bs[BK][BN];   // [k][n]

    const int bn = blockIdx.x * BN;
    const int bm = blockIdx.y * BM;
    const int tid = threadIdx.x;
    const int tx = tid & 15;       // 0..15 -> 4 cols each
    const int ty = tid >> 4;       // 0..15 -> 8 rows each

    float acc[8][4] = {};

    for (int k0 = 0; k0 < K; k0 += BK) {
        // Stage A tile (128 rows x 16 k): 512 float4 tasks, 2 per thread
        #pragma unroll
        for (int j = 0; j < 2; ++j) {
            const int s  = tid + 256 * j;
            const int r  = s >> 2;              // 0..127
            const int kk = (s & 3) << 2;        // 0,4,8,12
            float4 v = *(const float4*)&A[(size_t)(bm + r) * K + k0 + kk];
            As[kk + 0][r] = v.x;
            As[kk + 1][r] = v.y;
            As[kk + 2][r] = v.z;
            As[kk + 3][r] = v.w;
        }
        // Stage B tile (16 k x 64 n)
        {
            const int kk = tid >> 4;            // 0..15
            const int c  = (tid & 15) << 2;     // 0..60
            float4 v = *(const float4*)&B[(size_t)(k0 + kk) * N + bn + c];
            *(float4*)&Bs[kk][c] = v;
        }
        __syncthreads();

        #pragma unroll
        for (int kk = 0; kk < BK; ++kk) {
            const float4 a0 = *(const float4*)&As[kk][ty << 3];
            const float4 a1 = *(const float4*)&As[kk][(ty << 3) + 4];
            const float4 b4 = *(const float4*)&Bs[kk][tx << 2];
            const float a[8] = {a0.x, a0.y, a0.z, a0.w, a1.x, a1.y, a1.z, a1.w};
            const float b[4] = {b4.x, b4.y, b4.z, b4.w};
            #pragma unroll
            for (int i = 0; i < 8; ++i)
                #pragma unroll
                for (int j = 0; j < 4; ++j)
                    acc[i][j] += a[i] * b[j];
        }
        __syncthreads();
    }

    const float4 bia = *(const float4*)&bias[bn + (tx << 2)];
    #pragma unroll
    for (int i = 0; i < 8; ++i) {
        const int r = bm + (ty << 3) + i;
        float4 o;
        o.x = acc[i][0] + bia.x;
        o.y = acc[i][1] + bia.y;
        o.z = acc[i][2] + bia.z;
        o.w = acc[i][3] + bia.w;
        *(float4*)&C[(size_t)r * N + bn + (tx << 2)] = o;
    }
}

// ---------------- softmax over last-16, in place ----------------
__global__ __launch_bounds__(256) void softmax16_kernel(float* __restrict__ a, int rows)
{
    const int r = blockIdx.x * 256 + threadIdx.x;
    if (r >= rows) return;
    float* row = a + (size_t)r * 16;
    float v[16];
    float4* rv = (float4*)row;
    #pragma unroll
    for (int i = 0; i < 4; ++i) *(float4*)&v[i * 4] = rv[i];
    float mx = v[0];
    #pragma unroll
    for (int i = 1; i < 16; ++i) mx = fmaxf(mx, v[i]);
    float s = 0.f;
    #pragma unroll
    for (int i = 0; i < 16; ++i) { v[i] = __expf(v[i] - mx); s += v[i]; }
    const float inv = 1.f / s;
    #pragma unroll
    for (int i = 0; i < 16; ++i) v[i] *= inv;
    #pragma unroll
    for (int i = 0; i < 4; ++i) rv[i] = *(float4*)&v[i * 4];
}

// ---------------- deformable sampling + aggregation (v3: two-phase, branch-free) ----
// Block = 256 threads, 4 queries.
// Phase 1: 512 tasks (q,m,pt) -> LDS: 4 combined corner weights (attn-scaled,
//          validity-zeroed) + 4 clamped flat float-indices into value.
// Phase 2: thread (q,m,d4) owns 4 channels; pure ds_read+global_load+FMA loop.
// LDS layout padded so phase-2's 8 m-rows hit disjoint bank groups:
//   row stride 516 floats -> bank offset 4*m (conflict-free b128 reads).
// Reference quirk preserved: sample (l,p) weighted by attn[..., p, l].
__global__ __launch_bounds__(256) void sample_kernel_v3(
    const float* __restrict__ value,
    const float* __restrict__ off,
    const float* __restrict__ attn,
    float* __restrict__ out)
{
    __shared__ __align__(16) float lds_task[8][516];

    const int tid = threadIdx.x;
    const int qbase = blockIdx.x * 4;

    // ---- Phase 1: compute per-point weights + indices ----
    #pragma unroll
    for (int j = 0; j < 2; ++j) {
        const int t  = tid + 256 * j;
        const int q  = t >> 7;          // 0..3
        const int m  = (t >> 4) & 7;
        const int pt = t & 15;          // pt = l*4 + p
        const int l  = pt >> 2;
        const int p  = pt & 3;
        const int qi = qbase + q;
        const int lq = qi & (LQ - 1);
        const int n  = qi >> 14;

        const int Hl = 128 >> l;
        const int STARTS[4] = {0, 16384, 20480, 21504};

        const float2 oxy = *(const float2*)&off[(size_t)qi * 256 + m * 32 + pt * 2];
        const float w    = attn[(size_t)qi * 128 + m * 16 + p * 4 + l]; // transposed pairing

        const float refx = ((lq & 127) + 0.5f) * (1.0f / 128.0f);
        const float refy = ((lq >> 7)  + 0.5f) * (1.0f / 128.0f);

        const float x = refx * (float)Hl + oxy.x - 0.5f;
        const float y = refy * (float)Hl + oxy.y - 0.5f;
        const float x0f = floorf(x), y0f = floorf(y);
        const int x0 = (int)x0f, y0 = (int)y0f;
        const int x1 = x0 + 1,  y1 = y0 + 1;
        const float fx = x - x0f, fy = y - y0f;
        const float gx = 1.f - fx, gy = 1.f - fy;

        const float vx0 = (x0 >= 0 && x0 < Hl) ? 1.f : 0.f;
        const float vx1 = (x1 >= 0 && x1 < Hl) ? 1.f : 0.f;
        const float vy0 = (y0 >= 0 && y0 < Hl) ? 1.f : 0.f;
        const float vy1 = (y1 >= 0 && y1 < Hl) ? 1.f : 0.f;

        const int x0c = min(max(x0, 0), Hl - 1);
        const int x1c = min(max(x1, 0), Hl - 1);
        const int y0c = min(max(y0, 0), Hl - 1);
        const int y1c = min(max(y1, 0), Hl - 1);

        // flat float-index into value; includes n, level, row/col, head
        const int base = (n * LIN + STARTS[l]) * 256 + m * 32;
        const int i00 = base + (y0c * Hl + x0c) * 256;
        const int i01 = base + (y0c * Hl + x1c) * 256;
        const int i10 = base + (y1c * Hl + x0c) * 256;
        const int i11 = base + (y1c * Hl + x1c) * 256;

        float4 wv;
        wv.x = w * gy * gx * vy0 * vx0;
        wv.y = w * gy * fx * vy0 * vx1;
        wv.z = w * fy * gx * vy1 * vx0;
        wv.w = w * fy * fx * vy1 * vx1;

        float* dst = &lds_task[m][(q * 16 + pt) * 8];
        *(float4*)dst = wv;
        int4 iv = {i00, i01, i10, i11};
        *(int4*)(dst + 4) = iv;
    }
    __syncthreads();

    // ---- Phase 2: gather + weighted accumulate ----
    const int q  = tid >> 6;
    const int m  = (tid >> 3) & 7;
    const int d4 = tid & 7;
    const int qi = qbase + q;

    const float* vbase = value + d4 * 4;

    float4 acc = {0.f, 0.f, 0.f, 0.f};
    #pragma unroll
    for (int pt = 0; pt < 16; ++pt) {
        const float* td = &lds_task[m][(q * 16 + pt) * 8];
        const float4 wv = *(const float4*)td;
        const int4  iv = *(const int4*)(td + 4);
        const float4 v00 = *(const float4*)&vbase[iv.x];
        const float4 v01 = *(const float4*)&vbase[iv.y];
        const float4 v10 = *(const float4*)&vbase[iv.z];
        const float4 v11 = *(const float4*)&vbase[iv.w];
        acc.x += wv.x * v00.x + wv.y * v01.x + wv.z * v10.x + wv.w * v11.x;
        acc.y += wv.x * v00.y + wv.y * v01.y + wv.z * v10.y + wv.w * v11.y;
        acc.z += wv.x * v00.z + wv.y * v01.z + wv.z * v10.z + wv.w * v11.z;
        acc.w += wv.x * v00.w + wv.y * v01.w + wv.z * v10.w + wv.w * v11.w;
    }
    *(float4*)&out[(size_t)qi * 256 + m * 32 + d4 * 4] = acc;
}

// ---------------- launch ----------------
extern "C" void kernel_launch(void* const* d_in, const int* in_sizes, int n_in,
                              void* d_out, int out_size, void* d_ws, size_t ws_size,
                              hipStream_t stream)
{
    const float* query         = (const float*)d_in[0];
    const float* input_flatten = (const float*)d_in[2];
    const float* W_off  = (const float*)d_in[5];
    const float* b_off  = (const float*)d_in[6];
    const float* W_attn = (const float*)d_in[7];
    const float* b_attn = (const float*)d_in[8];
    const float* W_val  = (const float*)d_in[9];
    const float* b_val  = (const float*)d_in[10];
    const float* W_out  = (const float*)d_in[11];
    const float* b_out  = (const float*)d_in[12];
    float* out = (float*)d_out;

    // Workspace layout (floats): value | attn | sampled. off staged in d_out.
    float* ws      = (float*)d_ws;
    float* value   = ws;
    float* attnbuf = value + (size_t)43520 * 256;
    float* sampled = attnbuf + (size_t)32768 * 128;
    float* offbuf  = out;   // consumed before final GEMM overwrites d_out

    const int rowsA = NB * LQ;          // 32768
    const int rowsV = NB * LIN;         // 43520

    dim3 blk(256);

    // 1) value = input_flatten @ W_val + b_val
    gemm_f32<<<dim3(CDIM / BN, rowsV / BM), blk, 0, stream>>>(
        input_flatten, W_val, b_val, value, rowsV, CDIM, CDIM);

    // 2) off = query @ W_off + b_off   (into d_out scratch)
    gemm_f32<<<dim3(CDIM / BN, rowsA / BM), blk, 0, stream>>>(
        query, W_off, b_off, offbuf, rowsA, CDIM, CDIM);

    // 3) attn logits = query @ W_attn + b_attn
    gemm_f32<<<dim3(128 / BN, rowsA / BM), blk, 0, stream>>>(
        query, W_attn, b_attn, attnbuf, rowsA, 128, CDIM);

    // 4) softmax over 16 per (n,lq,m)
    softmax16_kernel<<<(rowsA * MH + 255) / 256, blk, 0, stream>>>(
        attnbuf, rowsA * MH);

    // 5) deformable sampling + aggregation (v3: two-phase, branch-free)
    sample_kernel_v3<<<rowsA / 4, blk, 0, stream>>>(value, offbuf, attnbuf, sampled);

    // 6) out = sampled @ W_out + b_out
    gemm_f32<<<dim3(CDIM / BN, rowsA / BM), blk, 0, stream>>>(
        sampled, W_out, b_out, out, rowsA, CDIM, CDIM);
}

// Round 4
// 299.924 us; speedup vs baseline: 2.3631x; 1.5011x over previous
//
#include <hip/hip_runtime.h>
#include <math.h>

// Problem constants (fixed by reference file)
#define NB   2
#define LQ   16384
#define CDIM 256
#define MH   8          // heads
#define DH   32         // head dim
#define LIN  21760      // 128^2+64^2+32^2+16^2

typedef __attribute__((ext_vector_type(8))) short bf16x8;
typedef __attribute__((ext_vector_type(4))) float f32x4;

// split f32 -> bf16 hi (truncate) + bf16 lo (residual, truncate)
// a ~= hi + lo with |err| ~ 2^-16 |a|
__device__ inline void split_bf16(float a, short& hi, short& lo) {
    unsigned int u = __float_as_uint(a);
    hi = (short)(u >> 16);
    float hf = __uint_as_float(u & 0xFFFF0000u);
    float l  = a - hf;
    lo = (short)(__float_as_uint(l) >> 16);
}

// ---------------- bf16x3 MFMA GEMM: C = A(MxK) @ B(KxN) + bias ----------------
// Tile: BM=128, BN=64, BK=32. 256 threads = 4 waves; wave w computes rows
// [w*32, w*32+32) x all 64 cols as 2x4 mfma_f32_16x16x32_bf16 tiles.
// 3-term emulation: acc += Ahi*Bhi + Ahi*Blo + Alo*Bhi  (~f32 accuracy).
// LDS: As[2][128][40] shorts (hi/lo planes, +8 pad -> 2-way conflicts only),
//      Bs[2][64][40] stored [n][k] with k-group XOR swizzle keyed on (n>>3)&3
//      (breaks 8-way write collision; reads conflict-free). All b128, 16B align.
#define GBM 128
#define GBN 64
#define GBK 32

__global__ __launch_bounds__(256) void gemm_bf16x3(
    const float* __restrict__ A, const float* __restrict__ B,
    const float* __restrict__ bias, float* __restrict__ C,
    int M, int N, int K)
{
    __shared__ short As[2][GBM][40];   // 20480 B
    __shared__ short Bs[2][GBN][40];   // 10240 B

    const int tid  = threadIdx.x;
    const int wave = tid >> 6;
    const int lane = tid & 63;
    const int quad = lane >> 4;        // 0..3
    const int l16  = lane & 15;
    const int bm = blockIdx.y * GBM;
    const int bn = blockIdx.x * GBN;
    const int wrow = wave * 32;

    f32x4 acc[2][4] = {};

    // B staging mapping: thread t -> column n = t&63, k-group kg = (t>>6)*8
    const int sn  = tid & 63;
    const int skg = (tid >> 6) * 8;
    const int skg_swz = skg ^ (((sn >> 3) & 3) << 3);   // XOR swizzle

    for (int k0 = 0; k0 < K; k0 += GBK) {
        // ---- stage A: 128 rows x 32 k. Thread handles 8 consecutive floats
        // of one row, twice (rows 0..63, then 64..127).
        #pragma unroll
        for (int p = 0; p < 2; ++p) {
            const int fb  = p * 512 + 2 * tid;      // float4-pair index
            const int row = fb >> 3;                // 0..127
            const int kq2 = (fb & 7) >> 1;          // 0..3 (8-float group)
            const float* ga = &A[(size_t)(bm + row) * K + k0 + kq2 * 8];
            float4 v0 = *(const float4*)ga;
            float4 v1 = *(const float4*)(ga + 4);
            union { short s[8]; uint4 v; } ph, pl;
            split_bf16(v0.x, ph.s[0], pl.s[0]);
            split_bf16(v0.y, ph.s[1], pl.s[1]);
            split_bf16(v0.z, ph.s[2], pl.s[2]);
            split_bf16(v0.w, ph.s[3], pl.s[3]);
            split_bf16(v1.x, ph.s[4], pl.s[4]);
            split_bf16(v1.y, ph.s[5], pl.s[5]);
            split_bf16(v1.z, ph.s[6], pl.s[6]);
            split_bf16(v1.w, ph.s[7], pl.s[7]);
            *(uint4*)&As[0][row][kq2 * 8] = ph.v;
            *(uint4*)&As[1][row][kq2 * 8] = pl.v;
        }
        // ---- stage B: 32 k x 64 n, transposed to [n][k] with swizzle.
        {
            union { short s[8]; uint4 v; } ph, pl;
            const float* gb = &B[(size_t)(k0 + skg) * N + bn + sn];
            #pragma unroll
            for (int j = 0; j < 8; ++j)
                split_bf16(gb[(size_t)j * N], ph.s[j], pl.s[j]);
            *(uint4*)&Bs[0][sn][skg_swz] = ph.v;
            *(uint4*)&Bs[1][sn][skg_swz] = pl.v;
        }
        __syncthreads();

        // ---- fragments + 24 MFMA
        bf16x8 a_h[2], a_l[2], b_h[4], b_l[4];
        #pragma unroll
        for (int r = 0; r < 2; ++r) {
            const int m = wrow + r * 16 + l16;
            a_h[r] = *(const bf16x8*)&As[0][m][quad * 8];
            a_l[r] = *(const bf16x8*)&As[1][m][quad * 8];
        }
        #pragma unroll
        for (int c = 0; c < 4; ++c) {
            const int n = c * 16 + l16;
            const int kswz = (quad ^ ((n >> 3) & 3)) * 8;
            b_h[c] = *(const bf16x8*)&Bs[0][n][kswz];
            b_l[c] = *(const bf16x8*)&Bs[1][n][kswz];
        }
        #pragma unroll
        for (int r = 0; r < 2; ++r)
            #pragma unroll
            for (int c = 0; c < 4; ++c) {
                acc[r][c] = __builtin_amdgcn_mfma_f32_16x16x32_bf16(
                    a_l[r], b_h[c], acc[r][c], 0, 0, 0);
                acc[r][c] = __builtin_amdgcn_mfma_f32_16x16x32_bf16(
                    a_h[r], b_l[c], acc[r][c], 0, 0, 0);
                acc[r][c] = __builtin_amdgcn_mfma_f32_16x16x32_bf16(
                    a_h[r], b_h[c], acc[r][c], 0, 0, 0);
            }
        __syncthreads();
    }

    // ---- epilogue: C/D layout col=lane&15, row=quad*4+reg
    #pragma unroll
    for (int c = 0; c < 4; ++c) {
        const int col = bn + c * 16 + l16;
        const float bia = bias[col];
        #pragma unroll
        for (int r = 0; r < 2; ++r) {
            #pragma unroll
            for (int i = 0; i < 4; ++i) {
                const int row = bm + wrow + r * 16 + quad * 4 + i;
                C[(size_t)row * N + col] = acc[r][c][i] + bia;
            }
        }
    }
}

// ---------------- softmax over last-16, in place ----------------
__global__ __launch_bounds__(256) void softmax16_kernel(float* __restrict__ a, int rows)
{
    const int r = blockIdx.x * 256 + threadIdx.x;
    if (r >= rows) return;
    float* row = a + (size_t)r * 16;
    float v[16];
    float4* rv = (float4*)row;
    #pragma unroll
    for (int i = 0; i < 4; ++i) *(float4*)&v[i * 4] = rv[i];
    float mx = v[0];
    #pragma unroll
    for (int i = 1; i < 16; ++i) mx = fmaxf(mx, v[i]);
    float s = 0.f;
    #pragma unroll
    for (int i = 0; i < 16; ++i) { v[i] = __expf(v[i] - mx); s += v[i]; }
    const float inv = 1.f / s;
    #pragma unroll
    for (int i = 0; i < 16; ++i) v[i] *= inv;
    #pragma unroll
    for (int i = 0; i < 4; ++i) rv[i] = *(float4*)&v[i * 4];
}

// ---------------- deformable sampling + aggregation (v3: two-phase, branch-free) ----
__global__ __launch_bounds__(256) void sample_kernel_v3(
    const float* __restrict__ value,
    const float* __restrict__ off,
    const float* __restrict__ attn,
    float* __restrict__ out)
{
    __shared__ __align__(16) float lds_task[8][516];

    const int tid = threadIdx.x;
    const int qbase = blockIdx.x * 4;

    // ---- Phase 1: compute per-point weights + indices ----
    #pragma unroll
    for (int j = 0; j < 2; ++j) {
        const int t  = tid + 256 * j;
        const int q  = t >> 7;          // 0..3
        const int m  = (t >> 4) & 7;
        const int pt = t & 15;          // pt = l*4 + p
        const int l  = pt >> 2;
        const int p  = pt & 3;
        const int qi = qbase + q;
        const int lq = qi & (LQ - 1);
        const int n  = qi >> 14;

        const int Hl = 128 >> l;
        const int STARTS[4] = {0, 16384, 20480, 21504};

        const float2 oxy = *(const float2*)&off[(size_t)qi * 256 + m * 32 + pt * 2];
        const float w    = attn[(size_t)qi * 128 + m * 16 + p * 4 + l]; // transposed pairing

        const float refx = ((lq & 127) + 0.5f) * (1.0f / 128.0f);
        const float refy = ((lq >> 7)  + 0.5f) * (1.0f / 128.0f);

        const float x = refx * (float)Hl + oxy.x - 0.5f;
        const float y = refy * (float)Hl + oxy.y - 0.5f;
        const float x0f = floorf(x), y0f = floorf(y);
        const int x0 = (int)x0f, y0 = (int)y0f;
        const int x1 = x0 + 1,  y1 = y0 + 1;
        const float fx = x - x0f, fy = y - y0f;
        const float gx = 1.f - fx, gy = 1.f - fy;

        const float vx0 = (x0 >= 0 && x0 < Hl) ? 1.f : 0.f;
        const float vx1 = (x1 >= 0 && x1 < Hl) ? 1.f : 0.f;
        const float vy0 = (y0 >= 0 && y0 < Hl) ? 1.f : 0.f;
        const float vy1 = (y1 >= 0 && y1 < Hl) ? 1.f : 0.f;

        const int x0c = min(max(x0, 0), Hl - 1);
        const int x1c = min(max(x1, 0), Hl - 1);
        const int y0c = min(max(y0, 0), Hl - 1);
        const int y1c = min(max(y1, 0), Hl - 1);

        const int base = (n * LIN + STARTS[l]) * 256 + m * 32;
        const int i00 = base + (y0c * Hl + x0c) * 256;
        const int i01 = base + (y0c * Hl + x1c) * 256;
        const int i10 = base + (y1c * Hl + x0c) * 256;
        const int i11 = base + (y1c * Hl + x1c) * 256;

        float4 wv;
        wv.x = w * gy * gx * vy0 * vx0;
        wv.y = w * gy * fx * vy0 * vx1;
        wv.z = w * fy * gx * vy1 * vx0;
        wv.w = w * fy * fx * vy1 * vx1;

        float* dst = &lds_task[m][(q * 16 + pt) * 8];
        *(float4*)dst = wv;
        int4 iv = {i00, i01, i10, i11};
        *(int4*)(dst + 4) = iv;
    }
    __syncthreads();

    // ---- Phase 2: gather + weighted accumulate ----
    const int q  = tid >> 6;
    const int m  = (tid >> 3) & 7;
    const int d4 = tid & 7;
    const int qi = qbase + q;

    const float* vbase = value + d4 * 4;

    float4 acc = {0.f, 0.f, 0.f, 0.f};
    #pragma unroll
    for (int pt = 0; pt < 16; ++pt) {
        const float* td = &lds_task[m][(q * 16 + pt) * 8];
        const float4 wv = *(const float4*)td;
        const int4  iv = *(const int4*)(td + 4);
        const float4 v00 = *(const float4*)&vbase[iv.x];
        const float4 v01 = *(const float4*)&vbase[iv.y];
        const float4 v10 = *(const float4*)&vbase[iv.z];
        const float4 v11 = *(const float4*)&vbase[iv.w];
        acc.x += wv.x * v00.x + wv.y * v01.x + wv.z * v10.x + wv.w * v11.x;
        acc.y += wv.x * v00.y + wv.y * v01.y + wv.z * v10.y + wv.w * v11.y;
        acc.z += wv.x * v00.z + wv.y * v01.z + wv.z * v10.z + wv.w * v11.z;
        acc.w += wv.x * v00.w + wv.y * v01.w + wv.z * v10.w + wv.w * v11.w;
    }
    *(float4*)&out[(size_t)qi * 256 + m * 32 + d4 * 4] = acc;
}

// ---------------- launch ----------------
extern "C" void kernel_launch(void* const* d_in, const int* in_sizes, int n_in,
                              void* d_out, int out_size, void* d_ws, size_t ws_size,
                              hipStream_t stream)
{
    const float* query         = (const float*)d_in[0];
    const float* input_flatten = (const float*)d_in[2];
    const float* W_off  = (const float*)d_in[5];
    const float* b_off  = (const float*)d_in[6];
    const float* W_attn = (const float*)d_in[7];
    const float* b_attn = (const float*)d_in[8];
    const float* W_val  = (const float*)d_in[9];
    const float* b_val  = (const float*)d_in[10];
    const float* W_out  = (const float*)d_in[11];
    const float* b_out  = (const float*)d_in[12];
    float* out = (float*)d_out;

    // Workspace layout (floats): value | attn | sampled. off staged in d_out.
    float* ws      = (float*)d_ws;
    float* value   = ws;
    float* attnbuf = value + (size_t)43520 * 256;
    float* sampled = attnbuf + (size_t)32768 * 128;
    float* offbuf  = out;   // consumed before final GEMM overwrites d_out

    const int rowsA = NB * LQ;          // 32768
    const int rowsV = NB * LIN;         // 43520

    dim3 blk(256);

    // 1) value = input_flatten @ W_val + b_val
    gemm_bf16x3<<<dim3(CDIM / GBN, rowsV / GBM), blk, 0, stream>>>(
        input_flatten, W_val, b_val, value, rowsV, CDIM, CDIM);

    // 2) off = query @ W_off + b_off   (into d_out scratch)
    gemm_bf16x3<<<dim3(CDIM / GBN, rowsA / GBM), blk, 0, stream>>>(
        query, W_off, b_off, offbuf, rowsA, CDIM, CDIM);

    // 3) attn logits = query @ W_attn + b_attn
    gemm_bf16x3<<<dim3(128 / GBN, rowsA / GBM), blk, 0, stream>>>(
        query, W_attn, b_attn, attnbuf, rowsA, 128, CDIM);

    // 4) softmax over 16 per (n,lq,m)
    softmax16_kernel<<<(rowsA * MH + 255) / 256, blk, 0, stream>>>(
        attnbuf, rowsA * MH);

    // 5) deformable sampling + aggregation (v3: two-phase, branch-free)
    sample_kernel_v3<<<rowsA / 4, blk, 0, stream>>>(value, offbuf, attnbuf, sampled);

    // 6) out = sampled @ W_out + b_out
    gemm_bf16x3<<<dim3(CDIM / GBN, rowsA / GBM), blk, 0, stream>>>(
        sampled, W_out, b_out, out, rowsA, CDIM, CDIM);
}